// Round 21
// baseline (233.534 us; speedup 1.0000x reference)
//
#include <hip/hip_runtime.h>
#include <hip/hip_bf16.h>
#include <math.h>

// HashMemory: B=8, S=4096, E=1024, Dm=512, M=64 slots.
// memory at step t == write_vals of tokens [t-64, t-1]  => window-64 attention.
// Pipeline: prep; WVQ = embb @ [W_write|W_query] (gemm_k64, fused WVT);
// attention (QBLK=32); out = R @ W_out (gemm_k64).
// r21: GEMM MFMA shape 16x16x32 -> 32x32x16 (higher pipe ceiling 2495 vs
// 2176 TF; half the MFMA instruction count per FLOP). LDS layout, staging,
// swizzle identical. C/D layout (HW-verified): col=lane&31,
// row=(reg&3)+8*(reg>>2)+4*(lane>>5). A/B operand: row=lane&31,
// k=(lane>>5)*8+e (family pattern of the verified 16x16x32 mapping).

#define BATCH   8
#define S_LEN   4096
#define EMB     1024
#define DM      512
#define MROWS   (BATCH * S_LEN)          // 32768
#define SCALE_F 0.04419417382415922f     // 512^-0.5

typedef __attribute__((ext_vector_type(4)))  float f32x4;
typedef __attribute__((ext_vector_type(16))) float f32x16;
typedef __attribute__((ext_vector_type(8)))  short short8;

__device__ __forceinline__ unsigned short f2bf(float f) {
    __hip_bfloat16 h = __float2bfloat16(f);
    return *reinterpret_cast<unsigned short*>(&h);
}

// ---------------------------------------------------------------------------
// Fused prep: emb f32->bf16 cast (blocks 0..32767), W_wr/W_qr/W_out
// transpose+cast (blocks 32768..38911), bias concat (block 38912).
// ---------------------------------------------------------------------------
__global__ __launch_bounds__(256) void prep(
    const float4* __restrict__ emb4, ushort4* __restrict__ embb4,
    const float* __restrict__ W_wr, const float* __restrict__ W_qr,
    const float* __restrict__ W_out,
    const float* __restrict__ b_wr, const float* __restrict__ b_qr,
    __hip_bfloat16* __restrict__ wcat, __hip_bfloat16* __restrict__ wout,
    float* __restrict__ bcat)
{
    const int bx = blockIdx.x;
    if (bx < 32768) {                              // emb cast: 8M float4
        int id = bx * 256 + threadIdx.x;
        float4 v = emb4[id];
        ushort4 o;
        o.x = f2bf(v.x); o.y = f2bf(v.y); o.z = f2bf(v.z); o.w = f2bf(v.w);
        embb4[id] = o;
    } else if (bx < 32768 + 2048) {                // wcat[0:512][1024] = W_wr^T
        int id = (bx - 32768) * 256 + threadIdx.x;
        int n = id >> 10, k = id & 1023;
        wcat[id] = __float2bfloat16(W_wr[k * 512 + n]);
    } else if (bx < 32768 + 4096) {                // wcat[512:1024][1024] = W_qr^T
        int id = (bx - 32768 - 2048) * 256 + threadIdx.x;
        int n = id >> 10, k = id & 1023;
        wcat[(size_t)DM * EMB + id] = __float2bfloat16(W_qr[k * 512 + n]);
    } else if (bx < 32768 + 6144) {                // wout[1024][512] = W_out^T
        int id = (bx - 32768 - 4096) * 256 + threadIdx.x;
        int n = id >> 9, k = id & 511;
        wout[id] = __float2bfloat16(W_out[k * 1024 + n]);
    } else {                                       // bias concat
        int i = threadIdx.x;
#pragma unroll
        for (int r = 0; r < 4; ++r, i += 256)
            bcat[i] = (i < 512) ? b_wr[i] : b_qr[i - 512];
    }
}

// ---------------------------------------------------------------------------
// GEMM: 256x256 tile, BK=64, 8 waves (2x4), 128KB LDS, 32x32x16 MFMA.
// Per wave: 4 m-tiles x 2 n-tiles of 32x32; 4 k-steps of 16; 32 MFMA/tile.
// B-frags once/tile in regs (8 reads), A-frags per m-tile (16 reads).
// ---------------------------------------------------------------------------
template<bool BF16OUT, bool TRANSLO>
__global__ __launch_bounds__(512, 2) void gemm_k64(
    const __hip_bfloat16* __restrict__ A, int lda,
    const __hip_bfloat16* __restrict__ Bt, int ldb,
    const float* __restrict__ bias,
    void* __restrict__ Cv, int ldc,
    __hip_bfloat16* __restrict__ wvtp,
    int K, int nbx)
{
    __shared__ __align__(16) char smem[131072];

    const int nwg = gridDim.x;
    const int bid = blockIdx.x;
    const int cpx = nwg >> 3;
    const int swz = (bid & 7) * cpx + (bid >> 3);
    const int bm0 = (swz / nbx) << 8;
    const int bn0 = (swz % nbx) << 8;

    const int tid  = threadIdx.x;
    const int lane = tid & 63;
    const int w    = tid >> 6;
    const int wm   = w >> 2, wn = w & 3;
    const int l31  = lane & 31, lh5 = lane >> 5;
    const int nt   = K >> 6;

    // staging: thread owns linear LDS slot tid*16 per 8KB region (64 rows x
    // 64 cols): row-in-region = tid>>3, phys chunk tid&7,
    // source chunk = (tid&7)^(row&7) (inverse swizzle).
    const int r64 = tid >> 3;
    const int cg8 = ((tid & 7) ^ (r64 & 7)) << 3;

    auto stage_tile = [&](int buf, int kt) {
#pragma unroll
        for (int h = 0; h < 4; ++h) {
            const int isB = h >> 1, hh = h & 1;
            const __hip_bfloat16* G = isB ? Bt : A;
            const int ldg = isB ? ldb : lda;
            const int rb  = (isB ? bn0 : bm0) + hh * 128;
#pragma unroll
            for (int i = 0; i < 2; ++i) {
                const __hip_bfloat16* g =
                    G + (size_t)(rb + i * 64 + r64) * ldg + kt + cg8;
                char* l = smem + buf * 65536 + isB * 32768 + hh * 16384
                          + i * 8192 + w * 1024;
                __builtin_amdgcn_global_load_lds(
                    (const __attribute__((address_space(1))) unsigned int*)g,
                    (__attribute__((address_space(3))) unsigned int*)l, 16, 0, 0);
            }
        }
    };

    f32x16 acc[4][2] = {};   // [m-tile][n-tile], 32x32 each

    stage_tile(0, 0);
    __syncthreads();

    for (int t = 0; t < nt; ++t) {
        const int cur = t & 1;
        const bool pf = (t + 1 < nt);
        if (pf) stage_tile(cur ^ 1, (t + 1) << 6);

        const char* sA = smem + cur * 65536;
        const char* sB = sA + 32768;

        // ---- B fragments: 8 reads, held for the whole tile ----
        // lane covers Bt-row (C-col) = wn*64 + ntile*32 + l31,
        // k = ks*16 + lh5*8 (+e)  -> 16B chunk index ks*2+lh5, swizzled.
        short8 bfv[2][4];                        // [ntile][ks]
#pragma unroll
        for (int nti = 0; nti < 2; ++nti) {
            const int r = wn * 64 + nti * 32 + l31;
#pragma unroll
            for (int ks = 0; ks < 4; ++ks) {
                const int pc = (ks * 2 + lh5) ^ (r & 7);
                bfv[nti][ks] = *(const short8*)(sB + r * 128 + (pc << 4));
            }
        }

        // ---- A per m-tile: 4 reads each; 8 MFMA per m-tile ----
#pragma unroll
        for (int mti = 0; mti < 4; ++mti) {
            const int r = wm * 128 + mti * 32 + l31;
            short8 af[4];
#pragma unroll
            for (int ks = 0; ks < 4; ++ks) {
                const int pc = (ks * 2 + lh5) ^ (r & 7);
                af[ks] = *(const short8*)(sA + r * 128 + (pc << 4));
            }
#pragma unroll
            for (int nti = 0; nti < 2; ++nti)
#pragma unroll
                for (int ks = 0; ks < 4; ++ks)
                    acc[mti][nti] = __builtin_amdgcn_mfma_f32_32x32x16_bf16(
                        af[ks], bfv[nti][ks], acc[mti][nti], 0, 0, 0);
        }

        if (pf) __syncthreads();
    }

    // ---- epilogue: C/D layout col=lane&31, row=(reg&3)+8*(reg>>2)+4*lh5 ----
    float bv[2];
#pragma unroll
    for (int nti = 0; nti < 2; ++nti)
        bv[nti] = bias[bn0 + wn * 64 + nti * 32 + l31];

#pragma unroll
    for (int mti = 0; mti < 4; ++mti) {
#pragma unroll
        for (int nti = 0; nti < 2; ++nti) {
            const int col = bn0 + wn * 64 + nti * 32 + l31;
#pragma unroll
            for (int rg = 0; rg < 4; ++rg) {      // reg group: rows rg*8+lh5*4+e
                const int row = bm0 + wm * 128 + mti * 32 + rg * 8 + lh5 * 4;
                float v[4];
#pragma unroll
                for (int e = 0; e < 4; ++e)
                    v[e] = acc[mti][nti][rg * 4 + e] + bv[nti];

#pragma unroll
                for (int e = 0; e < 4; ++e) {
                    if (BF16OUT)
                        ((__hip_bfloat16*)Cv)[(size_t)(row + e) * ldc + col] =
                            __float2bfloat16(v[e]);
                    else
                        ((float*)Cv)[(size_t)(row + e) * ldc + col] = v[e];
                }
                if (TRANSLO && col < 512) {
                    union { unsigned short s[4]; uint2 u; } tv;
#pragma unroll
                    for (int e = 0; e < 4; ++e) tv.s[e] = f2bf(v[e]);
                    *(uint2*)((unsigned short*)wvtp
                              + (((size_t)((row >> 12) * 512 + col)) << 12)
                              + (row & 4095)) = tv.u;
                }
            }
        }
    }
}

// ---------------------------------------------------------------------------
// MFMA windowed attention, QBLK=32: 2 waves/block, 1024 blocks (r16-exact).
// ---------------------------------------------------------------------------
__global__ __launch_bounds__(128) void attn_mfma32(
    const __hip_bfloat16* __restrict__ WVQ,   // [32768][1024]: 0:512=WV, 512:=Q
    const __hip_bfloat16* __restrict__ WVT,   // [8][512][4096]
    __hip_bfloat16* __restrict__ R)           // [32768][512]
{
    __shared__ __align__(16) unsigned short p_lds[32][104];  // 6656 B

    const int blk0 = blockIdx.x;                 // 1024 blocks, %8==0
    const int blk  = (blk0 & 7) * 128 + (blk0 >> 3);  // XCD-chunked (T1)
    const int b   = blk >> 7;                    // 128 blocks per batch
    const int t0  = (blk & 127) << 5;
    const int jmin = (t0 >= 64) ? 0 : 64 - t0;
    const size_t bbase = (size_t)b << 12;
    const int tid  = threadIdx.x;
    const int lane = tid & 63;
    const int w    = tid >> 6;                   // 0..1
    const int l15  = lane & 15;
    const int lhi  = lane >> 4;

    // ---- QK^T: S[32][96] ----
    f32x4 acc[6] = {};
    const __hip_bfloat16* q0 =
        WVQ + ((bbase + t0 + w * 16 + l15) << 10) + 512 + lhi * 8;

    const __hip_bfloat16* brow[6];
#pragma unroll
    for (int nt = 0; nt < 6; ++nt) {
        int aj = t0 - 64 + nt * 16 + l15;
        if (aj < 0) aj = 0;                 // clamped; masked below
        brow[nt] = WVQ + ((bbase + aj) << 10) + lhi * 8;
    }

#pragma unroll 2
    for (int kt = 0; kt < 16; ++kt) {
        short8 qa = *(const short8*)(q0 + kt * 32);
#pragma unroll
        for (int nt = 0; nt < 6; ++nt) {
            short8 bv = *(const short8*)(brow[nt] + kt * 32);
            acc[nt] = __builtin_amdgcn_mfma_f32_16x16x32_bf16(qa, bv, acc[nt], 0, 0, 0);
        }
    }

    // ---- wave-local softmax (rows i = w*16 + lhi*4 + reg) ----
    float m4[4] = { -1e30f, -1e30f, -1e30f, -1e30f };
#pragma unroll
    for (int nt = 0; nt < 6; ++nt)
#pragma unroll
        for (int reg = 0; reg < 4; ++reg) {
            int i = w * 16 + lhi * 4 + reg;
            int j = nt * 16 + l15;
            bool valid = (j >= i) && (j <= i + 63) && (j >= jmin);
            float s = valid ? acc[nt][reg] * SCALE_F : -1e30f;
            acc[nt][reg] = s;
            m4[reg] = fmaxf(m4[reg], s);
        }
#pragma unroll
    for (int off = 8; off >= 1; off >>= 1)
#pragma unroll
        for (int reg = 0; reg < 4; ++reg)
            m4[reg] = fmaxf(m4[reg], __shfl_xor(m4[reg], off, 64));

    float sum4[4] = {};
#pragma unroll
    for (int nt = 0; nt < 6; ++nt)
#pragma unroll
        for (int reg = 0; reg < 4; ++reg) {
            float s = acc[nt][reg];
            float p = (s > -1e29f) ? __expf(s - m4[reg]) : 0.f;
            acc[nt][reg] = p;
            sum4[reg] += p;
        }
#pragma unroll
    for (int off = 8; off >= 1; off >>= 1)
#pragma unroll
        for (int reg = 0; reg < 4; ++reg)
            sum4[reg] += __shfl_xor(sum4[reg], off, 64);

    float rs4[4];
#pragma unroll
    for (int reg = 0; reg < 4; ++reg)
        rs4[reg] = (sum4[reg] > 0.f) ? 1.f / sum4[reg] : 0.f;

#pragma unroll
    for (int nt = 0; nt < 6; ++nt)
#pragma unroll
        for (int reg = 0; reg < 4; ++reg)
            p_lds[w * 16 + lhi * 4 + reg][nt * 16 + l15] =
                f2bf(acc[nt][reg] * rs4[reg]);

    __syncthreads();

    // ---- PV: K-span 96 (3 k-steps) ----
    short8 pa[3];
#pragma unroll
    for (int kt = 0; kt < 3; ++kt)
        pa[kt] = *(const short8*)&p_lds[w * 16 + l15][kt * 32 + lhi * 8];

    int tclamp[3];
#pragma unroll
    for (int kt = 0; kt < 3; ++kt) {
        int ti = t0 - 64 + kt * 32 + lhi * 8;
        tclamp[kt] = ti < 0 ? 0 : ti;       // 8-chunks never straddle 0
    }

    const size_t vbase = (size_t)b * 512;
#pragma unroll 2
    for (int nt = 0; nt < 32; ++nt) {
        int d = nt * 16 + l15;
        f32x4 a = {};
#pragma unroll
        for (int kt = 0; kt < 3; ++kt) {
            short8 bv = *(const short8*)(WVT + ((vbase + d) << 12) + tclamp[kt]);
            a = __builtin_amdgcn_mfma_f32_16x16x32_bf16(pa[kt], bv, a, 0, 0, 0);
        }
        size_t rb = (bbase + t0 + w * 16 + lhi * 4) << 9;
#pragma unroll
        for (int reg = 0; reg < 4; ++reg)
            R[rb + ((size_t)reg << 9) + d] = __float2bfloat16(a[reg]);
    }
}

// ---------------------------------------------------------------------------
extern "C" void kernel_launch(void* const* d_in, const int* in_sizes, int n_in,
                              void* d_out, int out_size, void* d_ws, size_t ws_size,
                              hipStream_t stream)
{
    const float* emb   = (const float*)d_in[0];
    const float* W_wr  = (const float*)d_in[1];
    const float* b_wr  = (const float*)d_in[2];
    const float* W_qr  = (const float*)d_in[3];
    const float* b_qr  = (const float*)d_in[4];
    const float* W_out = (const float*)d_in[5];
    const float* b_out = (const float*)d_in[6];
    float* out = (float*)d_out;

    char* ws = (char*)d_ws;
    __hip_bfloat16* embb = (__hip_bfloat16*)(ws);                         // 0..64MB (dead after gemm1)
    __hip_bfloat16* rbuf = (__hip_bfloat16*)(ws);                         // 0..32MB (aliases dead embb)
    __hip_bfloat16* wvq  = (__hip_bfloat16*)(ws + (((size_t)64) << 20));  // 64..128MB
    __hip_bfloat16* wvt  = (__hip_bfloat16*)(ws + (((size_t)128) << 20)); // 128..160MB
    __hip_bfloat16* wcat = (__hip_bfloat16*)(ws + (((size_t)160) << 20)); // 2MB
    __hip_bfloat16* wout = (__hip_bfloat16*)(ws + (((size_t)162) << 20)); // 1MB
    float*          bcat = (float*)        (ws + (((size_t)163) << 20));  // 4KB

    prep<<<dim3(38913), dim3(256), 0, stream>>>(
        (const float4*)emb, (ushort4*)embb,
        W_wr, W_qr, W_out, b_wr, b_qr, wcat, wout, bcat);

    // WVQ = embb @ wcat^T + bcat (M=32768,N=1024,K=1024), bf16 out + WVT fused
    gemm_k64<true, true><<<dim3(512), dim3(512), 0, stream>>>(
        embb, EMB, wcat, EMB, bcat, (void*)wvq, 1024, wvt, EMB, 4);

    attn_mfma32<<<dim3(MROWS / 32), dim3(128), 0, stream>>>(wvq, wvt, rbuf);

    // out = rbuf @ wout^T + b_out  (M=32768, N=1024, K=512), f32 out
    gemm_k64<false, false><<<dim3(512), dim3(512), 0, stream>>>(
        rbuf, DM, wout, DM, b_out, (void*)out, EMB, nullptr, DM, 4);
}

// Round 22
// 222.414 us; speedup vs baseline: 1.0500x; 1.0500x over previous
//
#include <hip/hip_runtime.h>
#include <hip/hip_bf16.h>
#include <math.h>

// HashMemory: B=8, S=4096, E=1024, Dm=512, M=64 slots.
// memory at step t == write_vals of tokens [t-64, t-1]  => window-64 attention.
// Pipeline: prep; WVQ = embb @ [W_write|W_query] (gemm_k64, fused WVT);
// attention (QBLK=32, 2-wave blocks); out = R @ W_out (gemm_k64).
// r22: revert to r20/r16-exact (best measured 222.0-223.1us across 3 runs).
// r21's 32x32x16 MFMA regressed: 128B row stride => every row starts at
// bank 0; 8-chunk XOR swizzle covers 16-row reads (conflict-free) but a
// 32-row read has inherent 4-way conflicts (measured 6.29M). Search closed:
// schedules, occupancy, B-placement, MFMA shape, tiles all >= this config.

#define BATCH   8
#define S_LEN   4096
#define EMB     1024
#define DM      512
#define MROWS   (BATCH * S_LEN)          // 32768
#define SCALE_F 0.04419417382415922f     // 512^-0.5

typedef __attribute__((ext_vector_type(4))) float f32x4;
typedef __attribute__((ext_vector_type(8))) short short8;

__device__ __forceinline__ unsigned short f2bf(float f) {
    __hip_bfloat16 h = __float2bfloat16(f);
    return *reinterpret_cast<unsigned short*>(&h);
}

// ---------------------------------------------------------------------------
// Fused prep: emb f32->bf16 cast (blocks 0..32767), W_wr/W_qr/W_out
// transpose+cast (blocks 32768..38911), bias concat (block 38912).
// ---------------------------------------------------------------------------
__global__ __launch_bounds__(256) void prep(
    const float4* __restrict__ emb4, ushort4* __restrict__ embb4,
    const float* __restrict__ W_wr, const float* __restrict__ W_qr,
    const float* __restrict__ W_out,
    const float* __restrict__ b_wr, const float* __restrict__ b_qr,
    __hip_bfloat16* __restrict__ wcat, __hip_bfloat16* __restrict__ wout,
    float* __restrict__ bcat)
{
    const int bx = blockIdx.x;
    if (bx < 32768) {                              // emb cast: 8M float4
        int id = bx * 256 + threadIdx.x;
        float4 v = emb4[id];
        ushort4 o;
        o.x = f2bf(v.x); o.y = f2bf(v.y); o.z = f2bf(v.z); o.w = f2bf(v.w);
        embb4[id] = o;
    } else if (bx < 32768 + 2048) {                // wcat[0:512][1024] = W_wr^T
        int id = (bx - 32768) * 256 + threadIdx.x;
        int n = id >> 10, k = id & 1023;
        wcat[id] = __float2bfloat16(W_wr[k * 512 + n]);
    } else if (bx < 32768 + 4096) {                // wcat[512:1024][1024] = W_qr^T
        int id = (bx - 32768 - 2048) * 256 + threadIdx.x;
        int n = id >> 10, k = id & 1023;
        wcat[(size_t)DM * EMB + id] = __float2bfloat16(W_qr[k * 512 + n]);
    } else if (bx < 32768 + 6144) {                // wout[1024][512] = W_out^T
        int id = (bx - 32768 - 4096) * 256 + threadIdx.x;
        int n = id >> 9, k = id & 511;
        wout[id] = __float2bfloat16(W_out[k * 1024 + n]);
    } else {                                       // bias concat
        int i = threadIdx.x;
#pragma unroll
        for (int r = 0; r < 4; ++r, i += 256)
            bcat[i] = (i < 512) ? b_wr[i] : b_qr[i - 512];
    }
}

// ---------------------------------------------------------------------------
// GEMM (r12-exact): 256x256 tile, BK=64, 8 waves, 128KB LDS.
// B-frags once/tile in regs, A-frags once per mh. Optional fused WVT epilogue.
// ---------------------------------------------------------------------------
template<bool BF16OUT, bool TRANSLO>
__global__ __launch_bounds__(512, 2) void gemm_k64(
    const __hip_bfloat16* __restrict__ A, int lda,
    const __hip_bfloat16* __restrict__ Bt, int ldb,
    const float* __restrict__ bias,
    void* __restrict__ Cv, int ldc,
    __hip_bfloat16* __restrict__ wvtp,
    int K, int nbx)
{
    __shared__ __align__(16) char smem[131072];

    const int nwg = gridDim.x;
    const int bid = blockIdx.x;
    const int cpx = nwg >> 3;
    const int swz = (bid & 7) * cpx + (bid >> 3);
    const int bm0 = (swz / nbx) << 8;
    const int bn0 = (swz % nbx) << 8;

    const int tid  = threadIdx.x;
    const int lane = tid & 63;
    const int w    = tid >> 6;
    const int wm   = w >> 2, wn = w & 3;
    const int l15  = lane & 15, lhi = lane >> 4;
    const int nt   = K >> 6;

    const int r64 = tid >> 3;
    const int cg8 = ((tid & 7) ^ (r64 & 7)) << 3;

    auto stage_tile = [&](int buf, int kt) {
#pragma unroll
        for (int h = 0; h < 4; ++h) {
            const int isB = h >> 1, hh = h & 1;
            const __hip_bfloat16* G = isB ? Bt : A;
            const int ldg = isB ? ldb : lda;
            const int rb  = (isB ? bn0 : bm0) + hh * 128;
#pragma unroll
            for (int i = 0; i < 2; ++i) {
                const __hip_bfloat16* g =
                    G + (size_t)(rb + i * 64 + r64) * ldg + kt + cg8;
                char* l = smem + buf * 65536 + isB * 32768 + hh * 16384
                          + i * 8192 + w * 1024;
                __builtin_amdgcn_global_load_lds(
                    (const __attribute__((address_space(1))) unsigned int*)g,
                    (__attribute__((address_space(3))) unsigned int*)l, 16, 0, 0);
            }
        }
    };

    f32x4 acc[8][4] = {};

    stage_tile(0, 0);
    __syncthreads();

    for (int t = 0; t < nt; ++t) {
        const int cur = t & 1;
        const bool pf = (t + 1 < nt);
        if (pf) stage_tile(cur ^ 1, (t + 1) << 6);

        const char* sA = smem + cur * 65536;
        const char* sB = sA + 32768;

        short8 bfv[2][2][2];
#pragma unroll
        for (int nh = 0; nh < 2; ++nh)
#pragma unroll
            for (int ni = 0; ni < 2; ++ni) {
                const int r = wn * 64 + nh * 32 + ni * 16 + l15;
#pragma unroll
                for (int kk = 0; kk < 2; ++kk) {
                    const int pc = (kk * 4 + lhi) ^ (r & 7);
                    bfv[nh][ni][kk] = *(const short8*)(sB + r * 128 + (pc << 4));
                }
            }

#pragma unroll
        for (int mh = 0; mh < 2; ++mh) {
            short8 af[4][2];
#pragma unroll
            for (int mi = 0; mi < 4; ++mi) {
                const int r = wm * 128 + mh * 64 + mi * 16 + l15;
#pragma unroll
                for (int kk = 0; kk < 2; ++kk) {
                    const int pc = (kk * 4 + lhi) ^ (r & 7);
                    af[mi][kk] = *(const short8*)(sA + r * 128 + (pc << 4));
                }
            }
#pragma unroll
            for (int nh = 0; nh < 2; ++nh)
#pragma unroll
                for (int mi = 0; mi < 4; ++mi)
#pragma unroll
                    for (int ni = 0; ni < 2; ++ni)
#pragma unroll
                        for (int kk = 0; kk < 2; ++kk)
                            acc[mh * 4 + mi][nh * 2 + ni] =
                                __builtin_amdgcn_mfma_f32_16x16x32_bf16(
                                    af[mi][kk], bfv[nh][ni][kk],
                                    acc[mh * 4 + mi][nh * 2 + ni], 0, 0, 0);
        }

        if (pf) __syncthreads();
    }

    float bv[4];
#pragma unroll
    for (int N = 0; N < 4; ++N)
        bv[N] = bias[bn0 + wn * 64 + (N >> 1) * 32 + (N & 1) * 16 + l15];

#pragma unroll
    for (int M = 0; M < 8; ++M) {
        const int row = bm0 + wm * 128 + (M >> 2) * 64 + (M & 3) * 16 + lhi * 4;
#pragma unroll
        for (int N = 0; N < 4; ++N) {
            const int col = bn0 + wn * 64 + (N >> 1) * 32 + (N & 1) * 16 + l15;
            float v[4];
#pragma unroll
            for (int reg = 0; reg < 4; ++reg)
                v[reg] = acc[M][N][reg] + bv[N];

#pragma unroll
            for (int reg = 0; reg < 4; ++reg) {
                if (BF16OUT)
                    ((__hip_bfloat16*)Cv)[(size_t)(row + reg) * ldc + col] =
                        __float2bfloat16(v[reg]);
                else
                    ((float*)Cv)[(size_t)(row + reg) * ldc + col] = v[reg];
            }
            if (TRANSLO && col < 512) {
                union { unsigned short s[4]; uint2 u; } tv;
#pragma unroll
                for (int reg = 0; reg < 4; ++reg) tv.s[reg] = f2bf(v[reg]);
                *(uint2*)((unsigned short*)wvtp
                          + (((size_t)((row >> 12) * 512 + col)) << 12)
                          + (row & 4095)) = tv.u;
            }
        }
    }
}

// ---------------------------------------------------------------------------
// MFMA windowed attention, QBLK=32: 2 waves/block, 1024 blocks.
// Frame = 96 rows [t0-64, t0+31]. jmin = max(0, 64-t0).
// ---------------------------------------------------------------------------
__global__ __launch_bounds__(128) void attn_mfma32(
    const __hip_bfloat16* __restrict__ WVQ,   // [32768][1024]: 0:512=WV, 512:=Q
    const __hip_bfloat16* __restrict__ WVT,   // [8][512][4096]
    __hip_bfloat16* __restrict__ R)           // [32768][512]
{
    __shared__ __align__(16) unsigned short p_lds[32][104];  // 6656 B

    const int blk0 = blockIdx.x;                 // 1024 blocks, %8==0
    const int blk  = (blk0 & 7) * 128 + (blk0 >> 3);  // XCD-chunked (T1)
    const int b   = blk >> 7;                    // 128 blocks per batch
    const int t0  = (blk & 127) << 5;
    const int jmin = (t0 >= 64) ? 0 : 64 - t0;
    const size_t bbase = (size_t)b << 12;
    const int tid  = threadIdx.x;
    const int lane = tid & 63;
    const int w    = tid >> 6;                   // 0..1
    const int l15  = lane & 15;
    const int lhi  = lane >> 4;

    // ---- QK^T: S[32][96] ----
    f32x4 acc[6] = {};
    const __hip_bfloat16* q0 =
        WVQ + ((bbase + t0 + w * 16 + l15) << 10) + 512 + lhi * 8;

    const __hip_bfloat16* brow[6];
#pragma unroll
    for (int nt = 0; nt < 6; ++nt) {
        int aj = t0 - 64 + nt * 16 + l15;
        if (aj < 0) aj = 0;                 // clamped; masked below
        brow[nt] = WVQ + ((bbase + aj) << 10) + lhi * 8;
    }

#pragma unroll 2
    for (int kt = 0; kt < 16; ++kt) {
        short8 qa = *(const short8*)(q0 + kt * 32);
#pragma unroll
        for (int nt = 0; nt < 6; ++nt) {
            short8 bv = *(const short8*)(brow[nt] + kt * 32);
            acc[nt] = __builtin_amdgcn_mfma_f32_16x16x32_bf16(qa, bv, acc[nt], 0, 0, 0);
        }
    }

    // ---- wave-local softmax (rows i = w*16 + lhi*4 + reg) ----
    float m4[4] = { -1e30f, -1e30f, -1e30f, -1e30f };
#pragma unroll
    for (int nt = 0; nt < 6; ++nt)
#pragma unroll
        for (int reg = 0; reg < 4; ++reg) {
            int i = w * 16 + lhi * 4 + reg;
            int j = nt * 16 + l15;
            bool valid = (j >= i) && (j <= i + 63) && (j >= jmin);
            float s = valid ? acc[nt][reg] * SCALE_F : -1e30f;
            acc[nt][reg] = s;
            m4[reg] = fmaxf(m4[reg], s);
        }
#pragma unroll
    for (int off = 8; off >= 1; off >>= 1)
#pragma unroll
        for (int reg = 0; reg < 4; ++reg)
            m4[reg] = fmaxf(m4[reg], __shfl_xor(m4[reg], off, 64));

    float sum4[4] = {};
#pragma unroll
    for (int nt = 0; nt < 6; ++nt)
#pragma unroll
        for (int reg = 0; reg < 4; ++reg) {
            float s = acc[nt][reg];
            float p = (s > -1e29f) ? __expf(s - m4[reg]) : 0.f;
            acc[nt][reg] = p;
            sum4[reg] += p;
        }
#pragma unroll
    for (int off = 8; off >= 1; off >>= 1)
#pragma unroll
        for (int reg = 0; reg < 4; ++reg)
            sum4[reg] += __shfl_xor(sum4[reg], off, 64);

    float rs4[4];
#pragma unroll
    for (int reg = 0; reg < 4; ++reg)
        rs4[reg] = (sum4[reg] > 0.f) ? 1.f / sum4[reg] : 0.f;

#pragma unroll
    for (int nt = 0; nt < 6; ++nt)
#pragma unroll
        for (int reg = 0; reg < 4; ++reg)
            p_lds[w * 16 + lhi * 4 + reg][nt * 16 + l15] =
                f2bf(acc[nt][reg] * rs4[reg]);

    __syncthreads();

    // ---- PV: K-span 96 (3 k-steps) ----
    short8 pa[3];
#pragma unroll
    for (int kt = 0; kt < 3; ++kt)
        pa[kt] = *(const short8*)&p_lds[w * 16 + l15][kt * 32 + lhi * 8];

    int tclamp[3];
#pragma unroll
    for (int kt = 0; kt < 3; ++kt) {
        int ti = t0 - 64 + kt * 32 + lhi * 8;
        tclamp[kt] = ti < 0 ? 0 : ti;       // 8-chunks never straddle 0
    }

    const size_t vbase = (size_t)b * 512;
#pragma unroll 2
    for (int nt = 0; nt < 32; ++nt) {
        int d = nt * 16 + l15;
        f32x4 a = {};
#pragma unroll
        for (int kt = 0; kt < 3; ++kt) {
            short8 bv = *(const short8*)(WVT + ((vbase + d) << 12) + tclamp[kt]);
            a = __builtin_amdgcn_mfma_f32_16x16x32_bf16(pa[kt], bv, a, 0, 0, 0);
        }
        size_t rb = (bbase + t0 + w * 16 + lhi * 4) << 9;
#pragma unroll
        for (int reg = 0; reg < 4; ++reg)
            R[rb + ((size_t)reg << 9) + d] = __float2bfloat16(a[reg]);
    }
}

// ---------------------------------------------------------------------------
extern "C" void kernel_launch(void* const* d_in, const int* in_sizes, int n_in,
                              void* d_out, int out_size, void* d_ws, size_t ws_size,
                              hipStream_t stream)
{
    const float* emb   = (const float*)d_in[0];
    const float* W_wr  = (const float*)d_in[1];
    const float* b_wr  = (const float*)d_in[2];
    const float* W_qr  = (const float*)d_in[3];
    const float* b_qr  = (const float*)d_in[4];
    const float* W_out = (const float*)d_in[5];
    const float* b_out = (const float*)d_in[6];
    float* out = (float*)d_out;

    char* ws = (char*)d_ws;
    __hip_bfloat16* embb = (__hip_bfloat16*)(ws);                         // 0..64MB (dead after gemm1)
    __hip_bfloat16* rbuf = (__hip_bfloat16*)(ws);                         // 0..32MB (aliases dead embb)
    __hip_bfloat16* wvq  = (__hip_bfloat16*)(ws + (((size_t)64) << 20));  // 64..128MB
    __hip_bfloat16* wvt  = (__hip_bfloat16*)(ws + (((size_t)128) << 20)); // 128..160MB
    __hip_bfloat16* wcat = (__hip_bfloat16*)(ws + (((size_t)160) << 20)); // 2MB
    __hip_bfloat16* wout = (__hip_bfloat16*)(ws + (((size_t)162) << 20)); // 1MB
    float*          bcat = (float*)        (ws + (((size_t)163) << 20));  // 4KB

    prep<<<dim3(38913), dim3(256), 0, stream>>>(
        (const float4*)emb, (ushort4*)embb,
        W_wr, W_qr, W_out, b_wr, b_qr, wcat, wout, bcat);

    // WVQ = embb @ wcat^T + bcat (M=32768,N=1024,K=1024), bf16 out + WVT fused
    gemm_k64<true, true><<<dim3(512), dim3(512), 0, stream>>>(
        embb, EMB, wcat, EMB, bcat, (void*)wvq, 1024, wvt, EMB, 4);

    attn_mfma32<<<dim3(MROWS / 32), dim3(128), 0, stream>>>(wvq, wvt, rbuf);

    // out = rbuf @ wout^T + b_out  (M=32768, N=1024, K=512), f32 out
    gemm_k64<false, false><<<dim3(512), dim3(512), 0, stream>>>(
        rbuf, DM, wout, DM, b_out, (void*)out, EMB, nullptr, DM, 4);
}